// Round 6
// baseline (419.594 us; speedup 1.0000x reference)
//
#include <hip/hip_runtime.h>
#include <hip/hip_bf16.h>
#include <stdint.h>
#include <stddef.h>

// QuestionSpecificMLP R11 (= R10 + sanity-bounded ws gate).
//  Crash fault-tree: R8 (768 KB ws use) passed; R9/R10 (50 MB ws use) failed.
//  If ws_size is garbage-huge while the backing allocation is smaller, the
//  featG writes fault. Gate now requires WB_NEED <= ws_size < 64 GB; any
//  doubt routes to the byte-identical proven R8 fallback.
//  Split rationale (R5/R6/R8 evidence): fused dur invariant ~137 us across
//  occupancy 29-77%, hbm pinned at 1.13 TB/s = random-1.5KB-row DRAM ceiling
//  on the perm-gather of x. trunk_k reads x in NATURAL order (streams),
//  writes feat bf16 coalesced; head_k gathers feat (cache-resident) into
//  MFMA A-fragments and runs the proven per-head run loop.

typedef short s8v __attribute__((ext_vector_type(8)));   // 8 bf16 (4 VGPRs)
typedef float f4v __attribute__((ext_vector_type(4)));   // MFMA acc
typedef float f4a __attribute__((ext_vector_type(4), aligned(4)));  // 4B-aligned float4

typedef const void __attribute__((address_space(1))) *gas1_t;
typedef void __attribute__((address_space(3))) *las3_t;

namespace {
constexpr int kDin = 385;
constexpr int kDh  = 192;
constexpr int kQ   = 1000;
constexpr int kC   = 16;
constexpr int BM   = 64;
constexpr int NT   = 512;
constexpr int NK1  = 13;          // ceil(385/32), zero-padded
constexpr int NK2  = 6;           // 192/32
constexpr int CHUNK = 12 * 64 * 8;   // 6144 bf16 (12288 B) per swizzled k-chunk
constexpr int H2   = 200;         // bf16 stride for h / feat rows in LDS

// ---- fallback (small ws) layout: identical to proven R8 ------------------
constexpr size_t WS_W1   = 0;        // 159744
constexpr size_t WS_W2   = 163840;   // 73728 -> ends 237568
constexpr size_t WS_HIST = 245760;   // 2048*4 counts
constexpr size_t WS_CUR  = 253952;   // 2048*4 rank counters
constexpr size_t WS_PERM = 262144;   // 131072*4 -> ends at 768 KB

// ---- big layout (feat staged in ws) --------------------------------------
constexpr size_t WB_FEAT = 0;                         // 131072*192*2 = 50331648
constexpr size_t WB_W1   = 50331648;                  // 159744
constexpr size_t WB_W2   = WB_W1 + 159744;            // 50491392, 73728
constexpr size_t WB_HIST = WB_W2 + 73728;             // 50565120, 8192
constexpr size_t WB_CUR  = WB_HIST + 8192;            // 50573312, 8192
constexpr size_t WB_PERM = WB_CUR + 8192;             // 50581504, 524288
constexpr size_t WB_NEED = WB_PERM + 524288;          // 51105792
constexpr size_t WS_SANE_MAX = (1ull << 36);          // 64 GB: reject garbage
}

__device__ __forceinline__ unsigned short f2bf(float f) {
  unsigned int u = __float_as_uint(f);
  u = u + 0x7fffu + ((u >> 16) & 1u);       // RNE (non-NaN inputs)
  return (unsigned short)(u >> 16);
}

// packed pair: low 16 = bf16(lo), high 16 = bf16(hi); lowers to v_cvt_pk_bf16_f32
__device__ __forceinline__ unsigned int pk2(float lo, float hi) {
  union { __hip_bfloat162 h2; unsigned int u; } cv;
  cv.h2 = __float22bfloat162_rn(make_float2(lo, hi));
  return cv.u;
}

union s8u { s8v s; unsigned int u[4]; };

// ---- combined prep: histogram + both weight swizzles ---------------------
__device__ __forceinline__ void swz_one(const float* W, int K, int i,
                                        unsigned short* out) {
  int k = i / kDh;
  int c = i - k * kDh;
  float v = (k < K) ? W[(size_t)k * kDh + c] : 0.f;
  int oi = (k >> 5) * CHUNK + (((c >> 4) * 64 + ((k >> 3) & 3) * 16 + (c & 15)) << 3)
         + (k & 7);
  out[oi] = f2bf(v);
}

__global__ void combo_prep(const int* __restrict__ qid, const int* __restrict__ isc,
                           int B, int nbH,
                           const float* __restrict__ W1, const float* __restrict__ W2,
                           int* __restrict__ hist,
                           unsigned short* __restrict__ W1sw,
                           unsigned short* __restrict__ W2sw) {
  int bid = blockIdx.x;
  if (bid < nbH) {
    int i = bid * 256 + threadIdx.x;
    if (i < B) atomicAdd(&hist[qid[i] + isc[i] * kQ], 1);
  } else if (bid < nbH + 312) {                       // 312*256 = 416*192
    swz_one(W1, kDin, (bid - nbH) * 256 + threadIdx.x, W1sw);
  } else {                                            // 144*256 = 192*192
    swz_one(W2, kDh, (bid - nbH - 312) * 256 + threadIdx.x, W2sw);
  }
}

// ---- scan folded into scatter: each block recomputes the 2048-bin scan ----
__global__ __launch_bounds__(256)
void scatter2(const int* __restrict__ qid, const int* __restrict__ isc, int B,
              const int* __restrict__ hist, int* __restrict__ rank_ctr,
              int* __restrict__ perm) {
  __shared__ int sh[2048];
  __shared__ int ssum[256];
  int t = threadIdx.x;
  int4 a = ((const int4*)hist)[t * 2];
  int4 b = ((const int4*)hist)[t * 2 + 1];
  int s1 = a.x + a.y, s2 = s1 + a.z, s3 = s2 + a.w;
  int s4 = s3 + b.x, s5 = s4 + b.y, s6 = s5 + b.z, s7 = s6 + b.w;
  ssum[t] = s7;
  __syncthreads();
  #pragma unroll
  for (int d = 1; d < 256; d <<= 1) {
    int xv = (t >= d) ? ssum[t - d] : 0;
    __syncthreads();
    ssum[t] += xv;
    __syncthreads();
  }
  int base = ssum[t] - s7;                 // exclusive prefix over 8-bin groups
  sh[t * 8 + 0] = base;
  sh[t * 8 + 1] = base + a.x;
  sh[t * 8 + 2] = base + s1;
  sh[t * 8 + 3] = base + s2;
  sh[t * 8 + 4] = base + s3;
  sh[t * 8 + 5] = base + s4;
  sh[t * 8 + 6] = base + s5;
  sh[t * 8 + 7] = base + s6;
  __syncthreads();
  int i = blockIdx.x * 256 + t;
  if (i < B) {
    int h = qid[i] + isc[i] * kQ;
    int pos = sh[h] + atomicAdd(&rank_ctr[h], 1);
    perm[pos] = i;
  }
}

// ===========================================================================
//  BIG PATH: trunk (natural-order, streams x) + head (register A-fragments)
// ===========================================================================
__global__ __launch_bounds__(NT, 8)
void trunk_k(const float* __restrict__ x,
             const float* __restrict__ b1,
             const float* __restrict__ b2,
             const unsigned short* __restrict__ W1sw,
             const unsigned short* __restrict__ W2sw,
             unsigned short* __restrict__ featG) {
  __shared__ __align__(16) unsigned short hS[BM * H2];   // 25600 B
  __shared__ __align__(16) unsigned short bS[CHUNK];     // 12288 B

  const int tid  = threadIdx.x;
  const int lane = tid & 63, wid = tid >> 6;   // wid 0..7
  const int m = lane & 15, quad = lane >> 4;
  const int rh = wid >> 1, ch = wid & 1;
  const int row0 = blockIdx.x * BM;

  // stage W1 chunk 0
  {
    const char* g = (const char*)W1sw + (size_t)tid * 16;
    char* l = (char*)bS + ((tid >> 6) << 10);
    __builtin_amdgcn_global_load_lds((gas1_t)g, (las3_t)l, 16, 0, 0);
    if (tid < 256)
      __builtin_amdgcn_global_load_lds((gas1_t)(g + 8192), (las3_t)(l + 8192),
                                       16, 0, 0);
  }

  const float* px = x + (size_t)(row0 + rh * 16 + m) * kDin;   // NATURAL rows

  f4v acc[6];
  #pragma unroll
  for (int t = 0; t < 6; ++t) acc[t] = (f4v){0.f, 0.f, 0.f, 0.f};

  f4a c0 = *(const f4a*)(px + quad * 8);
  f4a c1 = *(const f4a*)(px + quad * 8 + 4);
  float tl = 0.f;
  __syncthreads();                       // chunk 0 resident

  // ------------- layer 1: h = relu(x @ W1 + b1), K padded to 416 ----------
  #pragma unroll
  for (int kk = 0; kk < NK1; ++kk) {
    s8v a;
    if (kk < NK1 - 1) {
      s8u ua;
      ua.u[0] = pk2(c0[0], c0[1]); ua.u[1] = pk2(c0[2], c0[3]);
      ua.u[2] = pk2(c1[0], c1[1]); ua.u[3] = pk2(c1[2], c1[3]);
      a = ua.s;
    } else {
      a = (s8v){0,0,0,0,0,0,0,0};
      a[0] = (short)f2bf(tl);             // tl==0 for quad!=0
    }

    #pragma unroll
    for (int t = 0; t < 6; ++t) {
      s8v b = *(const s8v*)&bS[((ch * 6 + t) * 64 + lane) * 8];
      acc[t] = __builtin_amdgcn_mfma_f32_16x16x32_bf16(a, b, acc[t], 0, 0, 0);
    }
    __syncthreads();                      // all waves done reading chunk kk

    {
      const unsigned short* np = (kk < NK1 - 1)
          ? W1sw + (size_t)(kk + 1) * CHUNK : W2sw;
      const char* g = (const char*)np + (size_t)tid * 16;
      char* l = (char*)bS + ((tid >> 6) << 10);
      __builtin_amdgcn_global_load_lds((gas1_t)g, (las3_t)l, 16, 0, 0);
      if (tid < 256)
        __builtin_amdgcn_global_load_lds((gas1_t)(g + 8192), (las3_t)(l + 8192),
                                         16, 0, 0);
    }
    if (kk < NK1 - 2) {
      c0 = *(const f4a*)(px + (kk + 1) * 32 + quad * 8);
      c1 = *(const f4a*)(px + (kk + 1) * 32 + quad * 8 + 4);
    } else if (kk == NK1 - 2) {
      tl = (quad == 0) ? px[384] : 0.f;
    }
    if (kk == NK1 - 1) {
      #pragma unroll
      for (int t = 0; t < 6; ++t) {
        int c = ch * 96 + t * 16 + m;
        float bb = b1[c];
        #pragma unroll
        for (int r4 = 0; r4 < 4; ++r4) {
          int r = rh * 16 + quad * 4 + r4;
          float v0 = acc[t][r4] + bb;
          hS[r * H2 + c] = f2bf(v0 > 0.f ? v0 : 0.f);
          acc[t][r4] = 0.f;
        }
      }
    }
    __syncthreads();                      // drains stage
  }

  // ------------- layer 2: feat = relu(h @ W2 + b2) ------------------------
  const int ar0 = (rh * 16 + m) * H2;
  #pragma unroll
  for (int k2 = 0; k2 < NK2; ++k2) {
    s8v a = *(const s8v*)&hS[ar0 + k2 * 32 + quad * 8];
    #pragma unroll
    for (int t = 0; t < 6; ++t) {
      s8v b = *(const s8v*)&bS[((ch * 6 + t) * 64 + lane) * 8];
      acc[t] = __builtin_amdgcn_mfma_f32_16x16x32_bf16(a, b, acc[t], 0, 0, 0);
    }
    __syncthreads();
    if (k2 < NK2 - 1) {
      const char* g = (const char*)(W2sw + (size_t)(k2 + 1) * CHUNK)
                    + (size_t)tid * 16;
      char* l = (char*)bS + ((tid >> 6) << 10);
      __builtin_amdgcn_global_load_lds((gas1_t)g, (las3_t)l, 16, 0, 0);
      if (tid < 256)
        __builtin_amdgcn_global_load_lds((gas1_t)(g + 8192), (las3_t)(l + 8192),
                                         16, 0, 0);
    } else {
      #pragma unroll
      for (int t = 0; t < 6; ++t) {
        int c = ch * 96 + t * 16 + m;
        float bb = b2[c];
        #pragma unroll
        for (int r4 = 0; r4 < 4; ++r4) {
          int r = rh * 16 + quad * 4 + r4;
          float v0 = acc[t][r4] + bb;
          hS[r * H2 + c] = f2bf(v0 > 0.f ? v0 : 0.f);
        }
      }
    }
    __syncthreads();
  }

  // ------------- feat -> global, fully coalesced (3 x 16 B per thread) ----
  #pragma unroll
  for (int j = 0; j < 3; ++j) {
    int e = tid + j * NT;                 // 0..1535 = 64 rows x 24 chunks
    int row = e / 24, c8 = e - row * 24;
    *(s8v*)&featG[(size_t)(row0 + row) * kDh + c8 * 8] =
        *(const s8v*)&hS[row * H2 + c8 * 8];
  }
}

__global__ __launch_bounds__(NT, 8)
void head_k(const int* __restrict__ qid, const int* __restrict__ isc,
            const float* __restrict__ Wh, const float* __restrict__ bh,
            const unsigned short* __restrict__ featG,
            const int* __restrict__ perm, float* __restrict__ out) {
  __shared__ int permS[BM];
  __shared__ int idxS[BM];

  const int tid  = threadIdx.x;
  const int lane = tid & 63, wid = tid >> 6;
  const int m = lane & 15, quad = lane >> 4;
  const int rh = wid >> 1, ch = wid & 1;
  const int row0 = blockIdx.x * BM;

  if (tid < BM) {
    int p = perm[row0 + tid];
    permS[tid] = p;
    idxS[tid] = qid[p] + isc[p] * kQ;
  }
  __syncthreads();

  const int w16 = rh * 16;
  // A-fragment direct from global: lane (m,quad) holds feat[perm[w16+m]],
  // k-slice [kk*32+quad*8, +8). feat is cache-resident (just written).
  const unsigned short* fp = featG + (size_t)permS[w16 + m] * kDh + quad * 8;
  s8v f[6];
  #pragma unroll
  for (int kk = 0; kk < 6; ++kk) f[kk] = *(const s8v*)(fp + kk * 32);

  const int hm = idxS[w16 + m];
  const s8v zf = (s8v){0,0,0,0,0,0,0,0};
  unsigned rem = 0xFFFFu;
  int runIdx = 0;
  while (rem) {
    int r0 = (int)__builtin_ctz(rem);
    int h = idxS[w16 + r0];                 // uniform (LDS broadcast)
    unsigned long long bal = __ballot(hm == h);
    unsigned mask16 = (unsigned)(bal & 0xFFFFu);
    rem &= ~mask16;
    if ((runIdx & 1) == ch) {               // parity-split runs across pair
      bool valid = (hm == h);
      const float* wq = Wh + ((size_t)h * kC + m) * kDh + quad * 8;
      f4v acch = (f4v){0.f, 0.f, 0.f, 0.f};
      #pragma unroll
      for (int kk = 0; kk < 6; ++kk) {
        float4 wlo = *(const float4*)(wq + kk * 32);
        float4 whi = *(const float4*)(wq + kk * 32 + 4);
        s8u ub;
        ub.u[0] = pk2(wlo.x, wlo.y);
        ub.u[1] = pk2(wlo.z, wlo.w);
        ub.u[2] = pk2(whi.x, whi.y);
        ub.u[3] = pk2(whi.z, whi.w);
        s8v afr = valid ? f[kk] : zf;
        acch = __builtin_amdgcn_mfma_f32_16x16x32_bf16(afr, ub.s, acch, 0, 0, 0);
      }
      float bhv = bh[(size_t)h * kC + m];
      #pragma unroll
      for (int reg = 0; reg < 4; ++reg) {
        int r = quad * 4 + reg;
        if ((mask16 >> r) & 1u)
          out[(size_t)permS[w16 + r] * kC + m] = acch[reg] + bhv;
      }
    }
    runIdx++;
  }
}

// ===========================================================================
//  FALLBACK: R8's proven fused kernel (perm-gathered x)
// ===========================================================================
__global__ __launch_bounds__(NT, 8)
void fused_qmlp8(const float* __restrict__ x,
                 const int*   __restrict__ qid,
                 const int*   __restrict__ isc,
                 const float* __restrict__ b1,
                 const float* __restrict__ b2,
                 const float* __restrict__ Wh,
                 const float* __restrict__ bh,
                 const unsigned short* __restrict__ W1sw,
                 const unsigned short* __restrict__ W2sw,
                 const int*   __restrict__ perm,
                 float* __restrict__ out) {
  __shared__ __align__(16) unsigned short hS[BM * H2];
  __shared__ __align__(16) unsigned short bS[CHUNK];
  __shared__ int permS[BM];
  __shared__ int idxS[BM];

  const int tid  = threadIdx.x;
  const int lane = tid & 63, wid = tid >> 6;
  const int m = lane & 15, quad = lane >> 4;
  const int rh = wid >> 1, ch = wid & 1;
  const int row0 = blockIdx.x * BM;

  {
    const char* g = (const char*)W1sw + (size_t)tid * 16;
    char* l = (char*)bS + ((tid >> 6) << 10);
    __builtin_amdgcn_global_load_lds((gas1_t)g, (las3_t)l, 16, 0, 0);
    if (tid < 256)
      __builtin_amdgcn_global_load_lds((gas1_t)(g + 8192), (las3_t)(l + 8192),
                                       16, 0, 0);
  }
  if (tid < BM) {
    int p = perm[row0 + tid];
    permS[tid] = p;
    idxS[tid] = qid[p] + isc[p] * kQ;
  }
  __syncthreads();

  const float* px = x + (size_t)permS[rh * 16 + m] * kDin;

  f4v acc[6];
  #pragma unroll
  for (int t = 0; t < 6; ++t) acc[t] = (f4v){0.f, 0.f, 0.f, 0.f};

  f4a c0 = *(const f4a*)(px + quad * 8);
  f4a c1 = *(const f4a*)(px + quad * 8 + 4);
  float tl = 0.f;

  #pragma unroll
  for (int kk = 0; kk < NK1; ++kk) {
    s8v a;
    if (kk < NK1 - 1) {
      s8u ua;
      ua.u[0] = pk2(c0[0], c0[1]); ua.u[1] = pk2(c0[2], c0[3]);
      ua.u[2] = pk2(c1[0], c1[1]); ua.u[3] = pk2(c1[2], c1[3]);
      a = ua.s;
    } else {
      a = (s8v){0,0,0,0,0,0,0,0};
      a[0] = (short)f2bf(tl);
    }

    #pragma unroll
    for (int t = 0; t < 6; ++t) {
      s8v b = *(const s8v*)&bS[((ch * 6 + t) * 64 + lane) * 8];
      acc[t] = __builtin_amdgcn_mfma_f32_16x16x32_bf16(a, b, acc[t], 0, 0, 0);
    }
    __syncthreads();

    {
      const unsigned short* np = (kk < NK1 - 1)
          ? W1sw + (size_t)(kk + 1) * CHUNK : W2sw;
      const char* g = (const char*)np + (size_t)tid * 16;
      char* l = (char*)bS + ((tid >> 6) << 10);
      __builtin_amdgcn_global_load_lds((gas1_t)g, (las3_t)l, 16, 0, 0);
      if (tid < 256)
        __builtin_amdgcn_global_load_lds((gas1_t)(g + 8192), (las3_t)(l + 8192),
                                         16, 0, 0);
    }
    if (kk < NK1 - 2) {
      c0 = *(const f4a*)(px + (kk + 1) * 32 + quad * 8);
      c1 = *(const f4a*)(px + (kk + 1) * 32 + quad * 8 + 4);
    } else if (kk == NK1 - 2) {
      tl = (quad == 0) ? px[384] : 0.f;
    }
    if (kk == NK1 - 1) {
      #pragma unroll
      for (int t = 0; t < 6; ++t) {
        int c = ch * 96 + t * 16 + m;
        float bb = b1[c];
        #pragma unroll
        for (int r4 = 0; r4 < 4; ++r4) {
          int r = rh * 16 + quad * 4 + r4;
          float v0 = acc[t][r4] + bb;
          hS[r * H2 + c] = f2bf(v0 > 0.f ? v0 : 0.f);
          acc[t][r4] = 0.f;
        }
      }
    }
    __syncthreads();
  }

  const int ar0 = (rh * 16 + m) * H2;
  #pragma unroll
  for (int k2 = 0; k2 < NK2; ++k2) {
    s8v a = *(const s8v*)&hS[ar0 + k2 * 32 + quad * 8];
    #pragma unroll
    for (int t = 0; t < 6; ++t) {
      s8v b = *(const s8v*)&bS[((ch * 6 + t) * 64 + lane) * 8];
      acc[t] = __builtin_amdgcn_mfma_f32_16x16x32_bf16(a, b, acc[t], 0, 0, 0);
    }
    __syncthreads();
    if (k2 < NK2 - 1) {
      const char* g = (const char*)(W2sw + (size_t)(k2 + 1) * CHUNK)
                    + (size_t)tid * 16;
      char* l = (char*)bS + ((tid >> 6) << 10);
      __builtin_amdgcn_global_load_lds((gas1_t)g, (las3_t)l, 16, 0, 0);
      if (tid < 256)
        __builtin_amdgcn_global_load_lds((gas1_t)(g + 8192), (las3_t)(l + 8192),
                                         16, 0, 0);
    } else {
      #pragma unroll
      for (int t = 0; t < 6; ++t) {
        int c = ch * 96 + t * 16 + m;
        float bb = b2[c];
        #pragma unroll
        for (int r4 = 0; r4 < 4; ++r4) {
          int r = rh * 16 + quad * 4 + r4;
          float v0 = acc[t][r4] + bb;
          hS[r * H2 + c] = f2bf(v0 > 0.f ? v0 : 0.f);
        }
      }
    }
    __syncthreads();
  }

  {
    const int w16 = rh * 16;
    const int hm = idxS[w16 + m];
    unsigned rem = 0xFFFFu;
    int runIdx = 0;
    while (rem) {
      int r0 = (int)__builtin_ctz(rem);
      int h = idxS[w16 + r0];
      unsigned long long bal = __ballot(hm == h);
      unsigned mask16 = (unsigned)(bal & 0xFFFFu);
      rem &= ~mask16;
      if ((runIdx & 1) == ch) {
        const float* wq = Wh + ((size_t)h * kC + m) * kDh + quad * 8;
        f4v acch = (f4v){0.f, 0.f, 0.f, 0.f};
        #pragma unroll
        for (int kk = 0; kk < 6; ++kk) {
          float4 wlo = *(const float4*)(wq + kk * 32);
          float4 whi = *(const float4*)(wq + kk * 32 + 4);
          s8u ub;
          ub.u[0] = pk2(wlo.x, wlo.y);
          ub.u[1] = pk2(wlo.z, wlo.w);
          ub.u[2] = pk2(whi.x, whi.y);
          ub.u[3] = pk2(whi.z, whi.w);
          s8v afr = *(const s8v*)&hS[(w16 + m) * H2 + kk * 32 + quad * 8];
          if (hm != h) afr = (s8v){0,0,0,0,0,0,0,0};
          acch = __builtin_amdgcn_mfma_f32_16x16x32_bf16(afr, ub.s, acch, 0, 0, 0);
        }
        float bhv = bh[(size_t)h * kC + m];
        #pragma unroll
        for (int reg = 0; reg < 4; ++reg) {
          int r = quad * 4 + reg;
          if ((mask16 >> r) & 1u)
            out[(size_t)permS[w16 + r] * kC + m] = acch[reg] + bhv;
        }
      }
      runIdx++;
    }
  }
}

extern "C" void kernel_launch(void* const* d_in, const int* in_sizes, int n_in,
                              void* d_out, int out_size, void* d_ws, size_t ws_size,
                              hipStream_t stream) {
  const float* x  = (const float*)d_in[0];
  const int*   qd = (const int*)  d_in[1];
  const int*   ic = (const int*)  d_in[2];
  const float* W1 = (const float*)d_in[3];
  const float* b1 = (const float*)d_in[4];
  const float* W2 = (const float*)d_in[5];
  const float* b2 = (const float*)d_in[6];
  const float* Wh = (const float*)d_in[7];
  const float* bh = (const float*)d_in[8];
  float* out = (float*)d_out;

  char* ws = (char*)d_ws;
  int B = in_sizes[1];   // 131072
  int nbH = (B + 255) / 256;

  const bool big = (d_ws != nullptr) && (ws_size >= WB_NEED)
                 && (ws_size < WS_SANE_MAX);

  if (big) {
    // ---- big path: trunk/head split ----
    unsigned short* featG = (unsigned short*)(ws + WB_FEAT);
    unsigned short* W1sw  = (unsigned short*)(ws + WB_W1);
    unsigned short* W2sw  = (unsigned short*)(ws + WB_W2);
    int* hist = (int*)(ws + WB_HIST);
    int* rank = (int*)(ws + WB_CUR);
    int* perm = (int*)(ws + WB_PERM);

    hipMemsetAsync(hist, 0, 4096 * sizeof(int), stream);
    combo_prep<<<nbH + 312 + 144, 256, 0, stream>>>(qd, ic, B, nbH, W1, W2,
                                                    hist, W1sw, W2sw);
    scatter2<<<(B + 255) / 256, 256, 0, stream>>>(qd, ic, B, hist, rank, perm);
    trunk_k<<<B / BM, NT, 0, stream>>>(x, b1, b2, W1sw, W2sw, featG);
    head_k<<<B / BM, NT, 0, stream>>>(qd, ic, Wh, bh, featG, perm, out);
  } else {
    // ---- fallback: proven R8 single fused kernel ----
    unsigned short* W1sw = (unsigned short*)(ws + WS_W1);
    unsigned short* W2sw = (unsigned short*)(ws + WS_W2);
    int* hist = (int*)(ws + WS_HIST);
    int* rank = (int*)(ws + WS_CUR);
    int* perm = (int*)(ws + WS_PERM);

    hipMemsetAsync(hist, 0, 4096 * sizeof(int), stream);
    combo_prep<<<nbH + 312 + 144, 256, 0, stream>>>(qd, ic, B, nbH, W1, W2,
                                                    hist, W1sw, W2sw);
    scatter2<<<(B + 255) / 256, 256, 0, stream>>>(qd, ic, B, hist, rank, perm);
    fused_qmlp8<<<B / BM, NT, 0, stream>>>(x, qd, ic, b1, b2, Wh, bh,
                                           W1sw, W2sw, perm, out);
  }
}

// Round 7
// 400.239 us; speedup vs baseline: 1.0484x; 1.0484x over previous
//
#include <hip/hip_runtime.h>
#include <hip/hip_bf16.h>
#include <stdint.h>
#include <stddef.h>

// QuestionSpecificMLP R12:
//  R11 evidence: trunk_k (natural-order x) = 127 us @ 1.36 TB/s, MfmaUtil 9.4%
//  -> NOT a DRAM ceiling; it's the 2-barriers-per-K-step schedule exposing
//  full memory latency per step (vmcnt(0) drain right after issue).
//  trunk_k2 = T3-minimum 2-phase pipeline:
//   - double-buffered bS, stage chunk k+1 + x-prefetch ISSUED BEFORE compute
//     of chunk k, ONE barrier per K-step (drain overlaps 12 MFMA + ds_reads)
//   - BM 64->128: 12 MFMA/wave/step, 21 barriers/block instead of 40
//   - hS wave-private (each wave owns its 16 rows end-to-end)
//  head_k / prep / ws-gate / fallback: unchanged from passing R11.

typedef short s8v __attribute__((ext_vector_type(8)));   // 8 bf16 (4 VGPRs)
typedef float f4v __attribute__((ext_vector_type(4)));   // MFMA acc
typedef float f4a __attribute__((ext_vector_type(4), aligned(4)));  // 4B-aligned float4

typedef const void __attribute__((address_space(1))) *gas1_t;
typedef void __attribute__((address_space(3))) *las3_t;

namespace {
constexpr int kDin = 385;
constexpr int kDh  = 192;
constexpr int kQ   = 1000;
constexpr int kC   = 16;
constexpr int BM   = 64;          // head_k / fallback row tile
constexpr int BM2  = 128;         // trunk_k2 row tile
constexpr int NT   = 512;
constexpr int NK1  = 13;          // ceil(385/32), zero-padded
constexpr int NK2  = 6;           // 192/32
constexpr int CHUNK = 12 * 64 * 8;   // 6144 bf16 (12288 B) per swizzled k-chunk
constexpr int H2   = 200;         // bf16 stride for h / feat rows in LDS

// ---- fallback (small ws) layout: identical to proven R8 ------------------
constexpr size_t WS_W1   = 0;        // 159744
constexpr size_t WS_W2   = 163840;   // 73728 -> ends 237568
constexpr size_t WS_HIST = 245760;   // 2048*4 counts
constexpr size_t WS_CUR  = 253952;   // 2048*4 rank counters
constexpr size_t WS_PERM = 262144;   // 131072*4 -> ends at 768 KB

// ---- big layout (feat staged in ws) --------------------------------------
constexpr size_t WB_FEAT = 0;                         // 131072*192*2 = 50331648
constexpr size_t WB_W1   = 50331648;                  // 159744
constexpr size_t WB_W2   = WB_W1 + 159744;            // 50491392, 73728
constexpr size_t WB_HIST = WB_W2 + 73728;             // 50565120, 8192
constexpr size_t WB_CUR  = WB_HIST + 8192;            // 50573312, 8192
constexpr size_t WB_PERM = WB_CUR + 8192;             // 50581504, 524288
constexpr size_t WB_NEED = WB_PERM + 524288;          // 51105792
constexpr size_t WS_SANE_MAX = (1ull << 36);          // 64 GB: reject garbage
}

__device__ __forceinline__ unsigned short f2bf(float f) {
  unsigned int u = __float_as_uint(f);
  u = u + 0x7fffu + ((u >> 16) & 1u);       // RNE (non-NaN inputs)
  return (unsigned short)(u >> 16);
}

// packed pair: low 16 = bf16(lo), high 16 = bf16(hi); lowers to v_cvt_pk_bf16_f32
__device__ __forceinline__ unsigned int pk2(float lo, float hi) {
  union { __hip_bfloat162 h2; unsigned int u; } cv;
  cv.h2 = __float22bfloat162_rn(make_float2(lo, hi));
  return cv.u;
}

union s8u { s8v s; unsigned int u[4]; };

// ---- combined prep: histogram + both weight swizzles ---------------------
__device__ __forceinline__ void swz_one(const float* W, int K, int i,
                                        unsigned short* out) {
  int k = i / kDh;
  int c = i - k * kDh;
  float v = (k < K) ? W[(size_t)k * kDh + c] : 0.f;
  int oi = (k >> 5) * CHUNK + (((c >> 4) * 64 + ((k >> 3) & 3) * 16 + (c & 15)) << 3)
         + (k & 7);
  out[oi] = f2bf(v);
}

__global__ void combo_prep(const int* __restrict__ qid, const int* __restrict__ isc,
                           int B, int nbH,
                           const float* __restrict__ W1, const float* __restrict__ W2,
                           int* __restrict__ hist,
                           unsigned short* __restrict__ W1sw,
                           unsigned short* __restrict__ W2sw) {
  int bid = blockIdx.x;
  if (bid < nbH) {
    int i = bid * 256 + threadIdx.x;
    if (i < B) atomicAdd(&hist[qid[i] + isc[i] * kQ], 1);
  } else if (bid < nbH + 312) {                       // 312*256 = 416*192
    swz_one(W1, kDin, (bid - nbH) * 256 + threadIdx.x, W1sw);
  } else {                                            // 144*256 = 192*192
    swz_one(W2, kDh, (bid - nbH - 312) * 256 + threadIdx.x, W2sw);
  }
}

// ---- scan folded into scatter: each block recomputes the 2048-bin scan ----
__global__ __launch_bounds__(256)
void scatter2(const int* __restrict__ qid, const int* __restrict__ isc, int B,
              const int* __restrict__ hist, int* __restrict__ rank_ctr,
              int* __restrict__ perm) {
  __shared__ int sh[2048];
  __shared__ int ssum[256];
  int t = threadIdx.x;
  int4 a = ((const int4*)hist)[t * 2];
  int4 b = ((const int4*)hist)[t * 2 + 1];
  int s1 = a.x + a.y, s2 = s1 + a.z, s3 = s2 + a.w;
  int s4 = s3 + b.x, s5 = s4 + b.y, s6 = s5 + b.z, s7 = s6 + b.w;
  ssum[t] = s7;
  __syncthreads();
  #pragma unroll
  for (int d = 1; d < 256; d <<= 1) {
    int xv = (t >= d) ? ssum[t - d] : 0;
    __syncthreads();
    ssum[t] += xv;
    __syncthreads();
  }
  int base = ssum[t] - s7;                 // exclusive prefix over 8-bin groups
  sh[t * 8 + 0] = base;
  sh[t * 8 + 1] = base + a.x;
  sh[t * 8 + 2] = base + s1;
  sh[t * 8 + 3] = base + s2;
  sh[t * 8 + 4] = base + s3;
  sh[t * 8 + 5] = base + s4;
  sh[t * 8 + 6] = base + s5;
  sh[t * 8 + 7] = base + s6;
  __syncthreads();
  int i = blockIdx.x * 256 + t;
  if (i < B) {
    int h = qid[i] + isc[i] * kQ;
    int pos = sh[h] + atomicAdd(&rank_ctr[h], 1);
    perm[pos] = i;
  }
}

// ---- async weight chunk staging: linear LDS, wave-uniform base -----------
__device__ __forceinline__ void stage2(const unsigned short* gsrc,
                                       unsigned short* lbase, int tid) {
  const char* g = (const char*)gsrc + (size_t)tid * 16;
  char* l = (char*)lbase + ((tid >> 6) << 10);
  __builtin_amdgcn_global_load_lds((gas1_t)g, (las3_t)l, 16, 0, 0);
  if (tid < 256)
    __builtin_amdgcn_global_load_lds((gas1_t)(g + 8192), (las3_t)(l + 8192),
                                     16, 0, 0);
}

// ===========================================================================
//  BIG PATH trunk: 2-phase pipelined, BM2=128, 1 barrier / K-step
// ===========================================================================
__global__ __launch_bounds__(NT, 4)
void trunk_k2(const float* __restrict__ x,
              const float* __restrict__ b1,
              const float* __restrict__ b2,
              const unsigned short* __restrict__ W1sw,
              const unsigned short* __restrict__ W2sw,
              unsigned short* __restrict__ featG) {
  __shared__ __align__(16) unsigned short hS[BM2 * H2];    // 51200 B
  __shared__ __align__(16) unsigned short bS[2 * CHUNK];   // 24576 B dbuf

  const int tid  = threadIdx.x;
  const int lane = tid & 63, wid = tid >> 6;   // wid 0..7
  const int m = lane & 15, quad = lane >> 4;
  const int w16 = wid * 16;                    // wave's private 16-row group
  const int row0 = blockIdx.x * BM2;

  const float* px = x + (size_t)(row0 + w16 + m) * kDin;   // natural rows

  // prologue: stage chunk 0 -> buf0; x for step 0
  stage2(W1sw, bS, tid);
  f4a c0 = *(const f4a*)(px + quad * 8);
  f4a c1 = *(const f4a*)(px + quad * 8 + 4);
  float tl = 0.f;

  f4v acc[12];
  #pragma unroll
  for (int t = 0; t < 12; ++t) acc[t] = (f4v){0.f, 0.f, 0.f, 0.f};
  __syncthreads();                         // chunk 0 resident

  // ------------- layer 1: g = 0..12 (13 steps, K padded to 416) -----------
  #pragma unroll
  for (int g = 0; g < NK1; ++g) {
    // issue next stage FIRST: latency overlaps this step's compute
    const unsigned short* np = (g < NK1 - 1)
        ? W1sw + (size_t)(g + 1) * CHUNK : W2sw;       // g==12 -> W2 chunk 0
    stage2(np, bS + ((g + 1) & 1) * CHUNK, tid);

    f4a n0, n1;
    if (g < NK1 - 2) {                       // x prefetch for step g+1
      n0 = *(const f4a*)(px + (g + 1) * 32 + quad * 8);
      n1 = *(const f4a*)(px + (g + 1) * 32 + quad * 8 + 4);
    } else if (g == NK1 - 2) {
      tl = (quad == 0) ? px[384] : 0.f;
    }

    s8v a;
    if (g < NK1 - 1) {
      s8u ua;
      ua.u[0] = pk2(c0[0], c0[1]); ua.u[1] = pk2(c0[2], c0[3]);
      ua.u[2] = pk2(c1[0], c1[1]); ua.u[3] = pk2(c1[2], c1[3]);
      a = ua.s;
    } else {                                 // only k==384 valid (quad0, j0)
      a = (s8v){0,0,0,0,0,0,0,0};
      a[0] = (short)f2bf(tl);
    }

    const unsigned short* bB = bS + (g & 1) * CHUNK;
    #pragma unroll
    for (int t = 0; t < 12; ++t) {
      s8v b = *(const s8v*)&bB[(t * 64 + lane) * 8];
      acc[t] = __builtin_amdgcn_mfma_f32_16x16x32_bf16(a, b, acc[t], 0, 0, 0);
    }

    if (g == NK1 - 1) {
      // epilogue 1 (wave-private rows): bias + relu -> hS bf16
      #pragma unroll
      for (int t = 0; t < 12; ++t) {
        int c = t * 16 + m;
        float bb = b1[c];
        #pragma unroll
        for (int r4 = 0; r4 < 4; ++r4) {
          int r = w16 + quad * 4 + r4;
          float v0 = acc[t][r4] + bb;
          hS[r * H2 + c] = f2bf(v0 > 0.f ? v0 : 0.f);
          acc[t][r4] = 0.f;
        }
      }
    }
    __syncthreads();     // ONE barrier: drains stage(g+1)+x(g+1); frees buf(g)
    if (g < NK1 - 2) { c0 = n0; c1 = n1; }
  }

  // ------------- layer 2: g = 13..18 (k2 = 0..5), parity continues --------
  #pragma unroll
  for (int k2 = 0; k2 < NK2; ++k2) {
    const int g = NK1 + k2;
    if (k2 < NK2 - 1)
      stage2(W2sw + (size_t)(k2 + 1) * CHUNK,
             bS + ((g + 1) & 1) * CHUNK, tid);

    // A from hS: wave-private rows (written by this wave in epilogue 1)
    s8v a = *(const s8v*)&hS[(w16 + m) * H2 + k2 * 32 + quad * 8];
    const unsigned short* bB = bS + (g & 1) * CHUNK;
    #pragma unroll
    for (int t = 0; t < 12; ++t) {
      s8v b = *(const s8v*)&bB[(t * 64 + lane) * 8];
      acc[t] = __builtin_amdgcn_mfma_f32_16x16x32_bf16(a, b, acc[t], 0, 0, 0);
    }
    if (k2 < NK2 - 1) __syncthreads();       // drain stage; free buf(g)
  }

  // epilogue 2 (wave-private rows): bias + relu -> hS bf16
  #pragma unroll
  for (int t = 0; t < 12; ++t) {
    int c = t * 16 + m;
    float bb = b2[c];
    #pragma unroll
    for (int r4 = 0; r4 < 4; ++r4) {
      int r = w16 + quad * 4 + r4;
      float v0 = acc[t][r4] + bb;
      hS[r * H2 + c] = f2bf(v0 > 0.f ? v0 : 0.f);
    }
  }
  __syncthreads();                           // cross-wave: copy reads all rows

  // feat -> global, fully coalesced (6 x 16 B per thread)
  #pragma unroll
  for (int j = 0; j < 6; ++j) {
    int e = tid + j * NT;                    // 0..3071 = 128 rows x 24 chunks
    int row = e / 24, c8 = e - row * 24;
    *(s8v*)&featG[(size_t)(row0 + row) * kDh + c8 * 8] =
        *(const s8v*)&hS[row * H2 + c8 * 8];
  }
}

// ===========================================================================
//  BIG PATH head: register A-fragments from cache-resident featG
// ===========================================================================
__global__ __launch_bounds__(NT, 8)
void head_k(const int* __restrict__ qid, const int* __restrict__ isc,
            const float* __restrict__ Wh, const float* __restrict__ bh,
            const unsigned short* __restrict__ featG,
            const int* __restrict__ perm, float* __restrict__ out) {
  __shared__ int permS[BM];
  __shared__ int idxS[BM];

  const int tid  = threadIdx.x;
  const int lane = tid & 63, wid = tid >> 6;
  const int m = lane & 15, quad = lane >> 4;
  const int rh = wid >> 1, ch = wid & 1;
  const int row0 = blockIdx.x * BM;

  if (tid < BM) {
    int p = perm[row0 + tid];
    permS[tid] = p;
    idxS[tid] = qid[p] + isc[p] * kQ;
  }
  __syncthreads();

  const int w16 = rh * 16;
  const unsigned short* fp = featG + (size_t)permS[w16 + m] * kDh + quad * 8;
  s8v f[6];
  #pragma unroll
  for (int kk = 0; kk < 6; ++kk) f[kk] = *(const s8v*)(fp + kk * 32);

  const int hm = idxS[w16 + m];
  const s8v zf = (s8v){0,0,0,0,0,0,0,0};
  unsigned rem = 0xFFFFu;
  int runIdx = 0;
  while (rem) {
    int r0 = (int)__builtin_ctz(rem);
    int h = idxS[w16 + r0];                 // uniform (LDS broadcast)
    unsigned long long bal = __ballot(hm == h);
    unsigned mask16 = (unsigned)(bal & 0xFFFFu);
    rem &= ~mask16;
    if ((runIdx & 1) == ch) {               // parity-split runs across pair
      bool valid = (hm == h);
      const float* wq = Wh + ((size_t)h * kC + m) * kDh + quad * 8;
      f4v acch = (f4v){0.f, 0.f, 0.f, 0.f};
      #pragma unroll
      for (int kk = 0; kk < 6; ++kk) {
        float4 wlo = *(const float4*)(wq + kk * 32);
        float4 whi = *(const float4*)(wq + kk * 32 + 4);
        s8u ub;
        ub.u[0] = pk2(wlo.x, wlo.y);
        ub.u[1] = pk2(wlo.z, wlo.w);
        ub.u[2] = pk2(whi.x, whi.y);
        ub.u[3] = pk2(whi.z, whi.w);
        s8v afr = valid ? f[kk] : zf;
        acch = __builtin_amdgcn_mfma_f32_16x16x32_bf16(afr, ub.s, acch, 0, 0, 0);
      }
      float bhv = bh[(size_t)h * kC + m];
      #pragma unroll
      for (int reg = 0; reg < 4; ++reg) {
        int r = quad * 4 + reg;
        if ((mask16 >> r) & 1u)
          out[(size_t)permS[w16 + r] * kC + m] = acch[reg] + bhv;
      }
    }
    runIdx++;
  }
}

// ===========================================================================
//  FALLBACK: R8's proven fused kernel (perm-gathered x)
// ===========================================================================
__global__ __launch_bounds__(NT, 8)
void fused_qmlp8(const float* __restrict__ x,
                 const int*   __restrict__ qid,
                 const int*   __restrict__ isc,
                 const float* __restrict__ b1,
                 const float* __restrict__ b2,
                 const float* __restrict__ Wh,
                 const float* __restrict__ bh,
                 const unsigned short* __restrict__ W1sw,
                 const unsigned short* __restrict__ W2sw,
                 const int*   __restrict__ perm,
                 float* __restrict__ out) {
  __shared__ __align__(16) unsigned short hS[BM * H2];
  __shared__ __align__(16) unsigned short bS[CHUNK];
  __shared__ int permS[BM];
  __shared__ int idxS[BM];

  const int tid  = threadIdx.x;
  const int lane = tid & 63, wid = tid >> 6;
  const int m = lane & 15, quad = lane >> 4;
  const int rh = wid >> 1, ch = wid & 1;
  const int row0 = blockIdx.x * BM;

  {
    const char* g = (const char*)W1sw + (size_t)tid * 16;
    char* l = (char*)bS + ((tid >> 6) << 10);
    __builtin_amdgcn_global_load_lds((gas1_t)g, (las3_t)l, 16, 0, 0);
    if (tid < 256)
      __builtin_amdgcn_global_load_lds((gas1_t)(g + 8192), (las3_t)(l + 8192),
                                       16, 0, 0);
  }
  if (tid < BM) {
    int p = perm[row0 + tid];
    permS[tid] = p;
    idxS[tid] = qid[p] + isc[p] * kQ;
  }
  __syncthreads();

  const float* px = x + (size_t)permS[rh * 16 + m] * kDin;

  f4v acc[6];
  #pragma unroll
  for (int t = 0; t < 6; ++t) acc[t] = (f4v){0.f, 0.f, 0.f, 0.f};

  f4a c0 = *(const f4a*)(px + quad * 8);
  f4a c1 = *(const f4a*)(px + quad * 8 + 4);
  float tl = 0.f;

  #pragma unroll
  for (int kk = 0; kk < NK1; ++kk) {
    s8v a;
    if (kk < NK1 - 1) {
      s8u ua;
      ua.u[0] = pk2(c0[0], c0[1]); ua.u[1] = pk2(c0[2], c0[3]);
      ua.u[2] = pk2(c1[0], c1[1]); ua.u[3] = pk2(c1[2], c1[3]);
      a = ua.s;
    } else {
      a = (s8v){0,0,0,0,0,0,0,0};
      a[0] = (short)f2bf(tl);
    }

    #pragma unroll
    for (int t = 0; t < 6; ++t) {
      s8v b = *(const s8v*)&bS[((ch * 6 + t) * 64 + lane) * 8];
      acc[t] = __builtin_amdgcn_mfma_f32_16x16x32_bf16(a, b, acc[t], 0, 0, 0);
    }
    __syncthreads();

    {
      const unsigned short* np = (kk < NK1 - 1)
          ? W1sw + (size_t)(kk + 1) * CHUNK : W2sw;
      const char* g = (const char*)np + (size_t)tid * 16;
      char* l = (char*)bS + ((tid >> 6) << 10);
      __builtin_amdgcn_global_load_lds((gas1_t)g, (las3_t)l, 16, 0, 0);
      if (tid < 256)
        __builtin_amdgcn_global_load_lds((gas1_t)(g + 8192), (las3_t)(l + 8192),
                                         16, 0, 0);
    }
    if (kk < NK1 - 2) {
      c0 = *(const f4a*)(px + (kk + 1) * 32 + quad * 8);
      c1 = *(const f4a*)(px + (kk + 1) * 32 + quad * 8 + 4);
    } else if (kk == NK1 - 2) {
      tl = (quad == 0) ? px[384] : 0.f;
    }
    if (kk == NK1 - 1) {
      #pragma unroll
      for (int t = 0; t < 6; ++t) {
        int c = ch * 96 + t * 16 + m;
        float bb = b1[c];
        #pragma unroll
        for (int r4 = 0; r4 < 4; ++r4) {
          int r = rh * 16 + quad * 4 + r4;
          float v0 = acc[t][r4] + bb;
          hS[r * H2 + c] = f2bf(v0 > 0.f ? v0 : 0.f);
          acc[t][r4] = 0.f;
        }
      }
    }
    __syncthreads();
  }

  const int ar0 = (rh * 16 + m) * H2;
  #pragma unroll
  for (int k2 = 0; k2 < NK2; ++k2) {
    s8v a = *(const s8v*)&hS[ar0 + k2 * 32 + quad * 8];
    #pragma unroll
    for (int t = 0; t < 6; ++t) {
      s8v b = *(const s8v*)&bS[((ch * 6 + t) * 64 + lane) * 8];
      acc[t] = __builtin_amdgcn_mfma_f32_16x16x32_bf16(a, b, acc[t], 0, 0, 0);
    }
    __syncthreads();
    if (k2 < NK2 - 1) {
      const char* g = (const char*)(W2sw + (size_t)(k2 + 1) * CHUNK)
                    + (size_t)tid * 16;
      char* l = (char*)bS + ((tid >> 6) << 10);
      __builtin_amdgcn_global_load_lds((gas1_t)g, (las3_t)l, 16, 0, 0);
      if (tid < 256)
        __builtin_amdgcn_global_load_lds((gas1_t)(g + 8192), (las3_t)(l + 8192),
                                         16, 0, 0);
    } else {
      #pragma unroll
      for (int t = 0; t < 6; ++t) {
        int c = ch * 96 + t * 16 + m;
        float bb = b2[c];
        #pragma unroll
        for (int r4 = 0; r4 < 4; ++r4) {
          int r = rh * 16 + quad * 4 + r4;
          float v0 = acc[t][r4] + bb;
          hS[r * H2 + c] = f2bf(v0 > 0.f ? v0 : 0.f);
        }
      }
    }
    __syncthreads();
  }

  {
    const int w16 = rh * 16;
    const int hm = idxS[w16 + m];
    unsigned rem = 0xFFFFu;
    int runIdx = 0;
    while (rem) {
      int r0 = (int)__builtin_ctz(rem);
      int h = idxS[w16 + r0];
      unsigned long long bal = __ballot(hm == h);
      unsigned mask16 = (unsigned)(bal & 0xFFFFu);
      rem &= ~mask16;
      if ((runIdx & 1) == ch) {
        const float* wq = Wh + ((size_t)h * kC + m) * kDh + quad * 8;
        f4v acch = (f4v){0.f, 0.f, 0.f, 0.f};
        #pragma unroll
        for (int kk = 0; kk < 6; ++kk) {
          float4 wlo = *(const float4*)(wq + kk * 32);
          float4 whi = *(const float4*)(wq + kk * 32 + 4);
          s8u ub;
          ub.u[0] = pk2(wlo.x, wlo.y);
          ub.u[1] = pk2(wlo.z, wlo.w);
          ub.u[2] = pk2(whi.x, whi.y);
          ub.u[3] = pk2(whi.z, whi.w);
          s8v afr = *(const s8v*)&hS[(w16 + m) * H2 + kk * 32 + quad * 8];
          if (hm != h) afr = (s8v){0,0,0,0,0,0,0,0};
          acch = __builtin_amdgcn_mfma_f32_16x16x32_bf16(afr, ub.s, acch, 0, 0, 0);
        }
        float bhv = bh[(size_t)h * kC + m];
        #pragma unroll
        for (int reg = 0; reg < 4; ++reg) {
          int r = quad * 4 + reg;
          if ((mask16 >> r) & 1u)
            out[(size_t)permS[w16 + r] * kC + m] = acch[reg] + bhv;
        }
      }
      runIdx++;
    }
  }
}

extern "C" void kernel_launch(void* const* d_in, const int* in_sizes, int n_in,
                              void* d_out, int out_size, void* d_ws, size_t ws_size,
                              hipStream_t stream) {
  const float* x  = (const float*)d_in[0];
  const int*   qd = (const int*)  d_in[1];
  const int*   ic = (const int*)  d_in[2];
  const float* W1 = (const float*)d_in[3];
  const float* b1 = (const float*)d_in[4];
  const float* W2 = (const float*)d_in[5];
  const float* b2 = (const float*)d_in[6];
  const float* Wh = (const float*)d_in[7];
  const float* bh = (const float*)d_in[8];
  float* out = (float*)d_out;

  char* ws = (char*)d_ws;
  int B = in_sizes[1];   // 131072
  int nbH = (B + 255) / 256;

  const bool big = (d_ws != nullptr) && (ws_size >= WB_NEED)
                 && (ws_size < WS_SANE_MAX);

  if (big) {
    // ---- big path: pipelined trunk + head ----
    unsigned short* featG = (unsigned short*)(ws + WB_FEAT);
    unsigned short* W1sw  = (unsigned short*)(ws + WB_W1);
    unsigned short* W2sw  = (unsigned short*)(ws + WB_W2);
    int* hist = (int*)(ws + WB_HIST);
    int* rank = (int*)(ws + WB_CUR);
    int* perm = (int*)(ws + WB_PERM);

    hipMemsetAsync(hist, 0, 4096 * sizeof(int), stream);
    combo_prep<<<nbH + 312 + 144, 256, 0, stream>>>(qd, ic, B, nbH, W1, W2,
                                                    hist, W1sw, W2sw);
    scatter2<<<(B + 255) / 256, 256, 0, stream>>>(qd, ic, B, hist, rank, perm);
    trunk_k2<<<B / BM2, NT, 0, stream>>>(x, b1, b2, W1sw, W2sw, featG);
    head_k<<<B / BM, NT, 0, stream>>>(qd, ic, Wh, bh, featG, perm, out);
  } else {
    // ---- fallback: proven R8 single fused kernel ----
    unsigned short* W1sw = (unsigned short*)(ws + WS_W1);
    unsigned short* W2sw = (unsigned short*)(ws + WS_W2);
    int* hist = (int*)(ws + WS_HIST);
    int* rank = (int*)(ws + WS_CUR);
    int* perm = (int*)(ws + WS_PERM);

    hipMemsetAsync(hist, 0, 4096 * sizeof(int), stream);
    combo_prep<<<nbH + 312 + 144, 256, 0, stream>>>(qd, ic, B, nbH, W1, W2,
                                                    hist, W1sw, W2sw);
    scatter2<<<(B + 255) / 256, 256, 0, stream>>>(qd, ic, B, hist, rank, perm);
    fused_qmlp8<<<B / BM, NT, 0, stream>>>(x, qd, ic, b1, b2, Wh, bh,
                                           W1sw, W2sw, perm, out);
  }
}